// Round 4
// baseline (370.992 us; speedup 1.0000x reference)
//
#include <hip/hip_runtime.h>
#include <hip/hip_bf16.h>
#include <stdint.h>

typedef __bf16 v8bf __attribute__((ext_vector_type(8)));
typedef float f32x4 __attribute__((ext_vector_type(4)));

__device__ __forceinline__ void gload_lds16(const void* g, void* l) {
    __builtin_amdgcn_global_load_lds(
        (const __attribute__((address_space(1))) void*)g,
        (__attribute__((address_space(3))) void*)l, 16, 0, 0);
}

__device__ __forceinline__ unsigned short f2bf(float f) {
    __hip_bfloat16 h = __float2bfloat16(f);
    return __builtin_bit_cast(unsigned short, h);
}

// ---- conversion kernels -------------------------------------------------
// xc = concat(x, c) along N axis, as bf16: [B=8][2048][512]
// total 8,388,608 elements = 2,097,152 float4 groups -> grid 8192 x 256
__global__ __launch_bounds__(256) void cvt_xc(const float* __restrict__ x,
                                              const float* __restrict__ c,
                                              __hip_bfloat16* __restrict__ xc) {
    int i = blockIdx.x * 256 + threadIdx.x;       // float4 index
    long e = (long)i * 4;
    int b = (int)(e >> 20);                       // 2048*512 = 1<<20
    int rem = (int)(e & ((1 << 20) - 1));
    int r = rem >> 9;
    int col = rem & 511;
    const float* src = (r < 1024) ? (x + ((long)b << 19) + (long)r * 512 + col)
                                  : (c + ((long)b << 19) + (long)(r - 1024) * 512 + col);
    float4 v = *(const float4*)src;
    ushort4 o;
    o.x = f2bf(v.x); o.y = f2bf(v.y); o.z = f2bf(v.z); o.w = f2bf(v.w);
    ((ushort4*)xc)[i] = o;
}

__global__ __launch_bounds__(256) void cvt_w(const float* __restrict__ q,
                                             const float* __restrict__ k,
                                             const float* __restrict__ v,
                                             const float* __restrict__ p,
                                             __hip_bfloat16* __restrict__ out) {
    int i = blockIdx.x * 256 + threadIdx.x;       // float4 index, 262,144 total
    int e = i * 4;
    int w = e >> 18;                              // 512*512 = 1<<18
    int off = e & ((1 << 18) - 1);
    const float* src = (w == 0 ? q : w == 1 ? k : w == 2 ? v : p) + off;
    float4 val = *(const float4*)src;
    ushort4 o;
    o.x = f2bf(val.x); o.y = f2bf(val.y); o.z = f2bf(val.z); o.w = f2bf(val.w);
    ((ushort4*)out)[i] = o;
}

// mask int32 [8][1024][2048] -> bit-packed uint64 [8][1024][32]
// one thread per mask element; wave ballot forms one 64-key word
__global__ __launch_bounds__(256) void cvt_mask(const int* __restrict__ mask,
                                                unsigned long long* __restrict__ mb) {
    long i = (long)blockIdx.x * 256 + threadIdx.x;   // 16,777,216 total
    int v = mask[i] != 0;
    unsigned long long bits = __ballot(v);
    if ((threadIdx.x & 63) == 0) mb[i >> 6] = bits;
}

// ---- GEMM: C[m,n] = sum_k A[m,k] * B[n,k]   (A: mapped rows of [.,512], B: [512][512])
// MODE 0: bf16 head-split out[((b*8+h)*seq + s)*64 + dh]
// MODE 1: bf16 transposed  out[((b*8+h)*64 + dh)*seq + s]   (V^T, seq=2048)
// MODE 2: fp32 plain       out[m*512 + n]
template <int MODE>
__global__ __launch_bounds__(256) void gemm_bt(const __hip_bfloat16* __restrict__ A,
                                               const __hip_bfloat16* __restrict__ Bw,
                                               void* __restrict__ outp,
                                               int row_div, int row_stride, int seq) {
    __shared__ __hip_bfloat16 As[128 * 32];
    __shared__ __hip_bfloat16 Bs[128 * 32];
    const int tid = threadIdx.x;
    const int wave = tid >> 6, lane = tid & 63;
    const int m0 = blockIdx.x * 128, n0 = blockIdx.y * 128;

    const int la = lane >> 2;            // row within 16-row chunk
    const int kc = (lane & 3) * 8;       // k element offset within 32-wide tile
    const int ra0 = m0 + wave * 16 + la;
    const int ra1 = m0 + (wave + 4) * 16 + la;
    const long ga0 = (long)((ra0 / row_div) * row_stride + (ra0 % row_div)) * 512 + kc;
    const long ga1 = (long)((ra1 / row_div) * row_stride + (ra1 % row_div)) * 512 + kc;
    const long gb0 = (long)(n0 + wave * 16 + la) * 512 + kc;
    const long gb1 = (long)(n0 + (wave + 4) * 16 + la) * 512 + kc;

    f32x4 acc[4][4] = {};
    const int mw = (wave & 1) * 64, nw = (wave >> 1) * 64;
    const int lrow = lane & 15, lk = (lane >> 4) * 8;

    for (int k0 = 0; k0 < 512; k0 += 32) {
        gload_lds16(A + ga0 + k0, &As[wave * 512]);
        gload_lds16(A + ga1 + k0, &As[(wave + 4) * 512]);
        gload_lds16(Bw + gb0 + k0, &Bs[wave * 512]);
        gload_lds16(Bw + gb1 + k0, &Bs[(wave + 4) * 512]);
        __syncthreads();
        v8bf a[4], b[4];
#pragma unroll
        for (int i = 0; i < 4; i++) {
            a[i] = *(const v8bf*)&As[(mw + i * 16 + lrow) * 32 + lk];
            b[i] = *(const v8bf*)&Bs[(nw + i * 16 + lrow) * 32 + lk];
        }
#pragma unroll
        for (int mi = 0; mi < 4; mi++)
#pragma unroll
            for (int ni = 0; ni < 4; ni++)
                acc[mi][ni] = __builtin_amdgcn_mfma_f32_16x16x32_bf16(a[mi], b[ni], acc[mi][ni], 0, 0, 0);
        __syncthreads();
    }

    const int lq = lane >> 4;
#pragma unroll
    for (int mi = 0; mi < 4; mi++) {
#pragma unroll
        for (int ni = 0; ni < 4; ni++) {
#pragma unroll
            for (int r = 0; r < 4; r++) {
                int grow = m0 + mw + mi * 16 + lq * 4 + r;
                int gcol = n0 + nw + ni * 16 + lrow;
                float val = acc[mi][ni][r];
                if (MODE == 2) {
                    ((float*)outp)[(long)grow * 512 + gcol] = val;
                } else {
                    int b_ = grow / seq, s = grow % seq;
                    int h = gcol >> 6, dh = gcol & 63;
                    long idx;
                    if (MODE == 0) idx = ((long)(b_ * 8 + h) * seq + s) * 64 + dh;
                    else           idx = ((long)(b_ * 8 + h) * 64 + dh) * (long)seq + s;
                    ((__hip_bfloat16*)outp)[idx] = __float2bfloat16(val);
                }
            }
        }
    }
}

// ---- flash attention ----------------------------------------------------
// grid: 1024 blocks, 1-D, XCD-swizzled: b = L&7 (pins batch->XCD), h = L>>7,
// qt = (L>>3)&15 (K/V of one head reused by 16 consecutive same-XCD blocks).
// block 256 = 4 waves; q-tile 64, k-tile 64. Mask is bit-packed (cvt_mask).
__global__ __launch_bounds__(256) void flash(const __hip_bfloat16* __restrict__ Q,
                                             const __hip_bfloat16* __restrict__ K,
                                             const __hip_bfloat16* __restrict__ Vt,
                                             const unsigned long long* __restrict__ Mb,
                                             __hip_bfloat16* __restrict__ Y) {
    constexpr int LDT = 72;  // padded stride: breaks 16-way bank conflict on b128 frag reads
    __shared__ __hip_bfloat16 Qs[64 * LDT], Ks[64 * LDT], Vts[64 * LDT];
    __shared__ __hip_bfloat16 Ps[4][16 * LDT];

    const int L = blockIdx.x;
    const int b = L & 7, h = L >> 7, qt = (L >> 3) & 15;
    const int bh = b * 8 + h;
    const int tid = threadIdx.x, wave = tid >> 6, lane = tid & 63;
    const __hip_bfloat16* Qp = Q + ((long)bh * 1024 + qt * 64) * 64;
    const __hip_bfloat16* Kp = K + (long)bh * 2048 * 64;
    const __hip_bfloat16* Vp = Vt + (long)bh * 64 * 2048;
    const unsigned long long* Mp = Mb + ((long)b * 1024 + qt * 64) * 32;

    {   // load Q tile [64 q][64 dh], padded
        const uint4* src = (const uint4*)Qp;
#pragma unroll
        for (int i = 0; i < 2; i++) {
            int u = tid + i * 256, r = u >> 3, part = u & 7;
            *(uint4*)&Qs[r * LDT + part * 8] = src[u];
        }
    }

    float mrow[4], lsum[4];
    f32x4 Oacc[4] = {};
#pragma unroll
    for (int r = 0; r < 4; r++) { mrow[r] = -3e38f; lsum[r] = 0.f; }

    const int lcol = lane & 15, lq = lane >> 4;

    for (int kt = 0; kt < 32; kt++) {
        // mask words for this wave's 4 q-rows (broadcast across 16 lanes; one
        // 8B fetch per row group; issued early so latency hides under staging+MFMA)
        unsigned long long mbits[4];
#pragma unroll
        for (int r = 0; r < 4; r++)
            mbits[r] = Mp[(wave * 16 + lq * 4 + r) * 32 + kt] >> lcol;

        {   // stage K tile [64 key][64 dh]
            const uint4* src = (const uint4*)(Kp + kt * 64 * 64);
#pragma unroll
            for (int i = 0; i < 2; i++) {
                int u = tid + i * 256, r = u >> 3, part = u & 7;
                *(uint4*)&Ks[r * LDT + part * 8] = src[u];
            }
            // stage V^T tile [64 dh][64 key]
#pragma unroll
            for (int i = 0; i < 2; i++) {
                int u = tid + i * 256, dh = u >> 3, part = u & 7;
                *(uint4*)&Vts[dh * LDT + part * 8] = *(const uint4*)(Vp + (long)dh * 2048 + kt * 64 + part * 8);
            }
        }
        __syncthreads();

        // S = Q K^T  (wave owns q rows [wave*16, wave*16+16), all 64 keys)
        f32x4 S[4] = {};
#pragma unroll
        for (int ks = 0; ks < 2; ks++) {
            v8bf aq = *(const v8bf*)&Qs[(wave * 16 + lcol) * LDT + ks * 32 + lq * 8];
#pragma unroll
            for (int nt = 0; nt < 4; nt++) {
                v8bf bk = *(const v8bf*)&Ks[(nt * 16 + lcol) * LDT + ks * 32 + lq * 8];
                S[nt] = __builtin_amdgcn_mfma_f32_16x16x32_bf16(aq, bk, S[nt], 0, 0, 0);
            }
        }
        // scale + mask (C-layout: row = lq*4+r, col = nt*16+lcol; bit nt*16 of mbits>>lcol)
        float p[4][4];
#pragma unroll
        for (int nt = 0; nt < 4; nt++)
#pragma unroll
            for (int r = 0; r < 4; r++) {
                float s = S[nt][r] * 0.125f;
                if ((mbits[r] >> (nt * 16)) & 1ull) s = -1e30f;
                p[nt][r] = s;
            }
        // online softmax (4 rows per lane, replicated over 16-lane groups)
        float mnew[4], alpha[4];
#pragma unroll
        for (int r = 0; r < 4; r++) {
            float mx = fmaxf(fmaxf(p[0][r], p[1][r]), fmaxf(p[2][r], p[3][r]));
            mx = fmaxf(mx, __shfl_xor(mx, 1));
            mx = fmaxf(mx, __shfl_xor(mx, 2));
            mx = fmaxf(mx, __shfl_xor(mx, 4));
            mx = fmaxf(mx, __shfl_xor(mx, 8));
            mnew[r] = fmaxf(mrow[r], mx);
            alpha[r] = __expf(mrow[r] - mnew[r]);
            mrow[r] = mnew[r];
        }
#pragma unroll
        for (int r = 0; r < 4; r++) {
            float sum = 0.f;
#pragma unroll
            for (int nt = 0; nt < 4; nt++) {
                float e = __expf(p[nt][r] - mnew[r]);
                p[nt][r] = e;
                sum += e;
            }
            sum += __shfl_xor(sum, 1);
            sum += __shfl_xor(sum, 2);
            sum += __shfl_xor(sum, 4);
            sum += __shfl_xor(sum, 8);
            lsum[r] = lsum[r] * alpha[r] + sum;
#pragma unroll
            for (int nt = 0; nt < 4; nt++) Oacc[nt][r] *= alpha[r];
        }
        // P: C-layout -> LDS (wave-private; compiler's lgkmcnt orders write->read,
        // no __syncthreads needed here)
#pragma unroll
        for (int nt = 0; nt < 4; nt++)
#pragma unroll
            for (int r = 0; r < 4; r++)
                Ps[wave][(lq * 4 + r) * LDT + nt * 16 + lcol] = __float2bfloat16(p[nt][r]);

        // O += P @ V   (A = P [16 q][64 key], B = V [64 key][64 dh] via Vts)
#pragma unroll
        for (int ks = 0; ks < 2; ks++) {
            v8bf ap = *(const v8bf*)&Ps[wave][lcol * LDT + ks * 32 + lq * 8];
#pragma unroll
            for (int nt = 0; nt < 4; nt++) {
                v8bf bv = *(const v8bf*)&Vts[(nt * 16 + lcol) * LDT + ks * 32 + lq * 8];
                Oacc[nt] = __builtin_amdgcn_mfma_f32_16x16x32_bf16(ap, bv, Oacc[nt], 0, 0, 0);
            }
        }
        __syncthreads();   // protects Ks/Vts before next iteration's staging
    }

    // epilogue: y[b, q, h*64+dh] bf16 (head-interleaved for the final GEMM)
#pragma unroll
    for (int r = 0; r < 4; r++) {
        float inv = 1.f / lsum[r];
#pragma unroll
        for (int nt = 0; nt < 4; nt++) {
            long row = (long)b * 1024 + qt * 64 + wave * 16 + lq * 4 + r;
            int col = h * 64 + nt * 16 + lcol;
            Y[row * 512 + col] = __float2bfloat16(Oacc[nt][r] * inv);
        }
    }
}

// ---- launch -------------------------------------------------------------
extern "C" void kernel_launch(void* const* d_in, const int* in_sizes, int n_in,
                              void* d_out, int out_size, void* d_ws, size_t ws_size,
                              hipStream_t stream) {
    const float* x = (const float*)d_in[0];
    const float* c = (const float*)d_in[1];
    const int* mask = (const int*)d_in[2];
    const float* Wq = (const float*)d_in[3];
    const float* Wk = (const float*)d_in[4];
    const float* Wv = (const float*)d_in[5];
    const float* Wp = (const float*)d_in[6];

    char* ws = (char*)d_ws;
    __hip_bfloat16* xc  = (__hip_bfloat16*)(ws);                 // 16,777,216 B (dead after V gemm)
    __hip_bfloat16* Wbf = (__hip_bfloat16*)(ws + 16777216);      //  2,097,152 B
    __hip_bfloat16* Qw  = (__hip_bfloat16*)(ws + 18874368);      //  8,388,608 B
    __hip_bfloat16* Kw  = (__hip_bfloat16*)(ws + 27262976);      // 16,777,216 B
    __hip_bfloat16* Vtw = (__hip_bfloat16*)(ws + 44040192);      // 16,777,216 B
    __hip_bfloat16* Yb  = (__hip_bfloat16*)(ws + 60817408);      //  8,388,608 B
    unsigned long long* Mbp = (unsigned long long*)(ws);         //  2,097,152 B, aliases dead xc

    cvt_xc<<<8192, 256, 0, stream>>>(x, c, xc);
    cvt_w<<<1024, 256, 0, stream>>>(Wq, Wk, Wv, Wp, Wbf);
    // Q: M=8192 (x rows only: row -> (r/1024)*2048 + r%1024), out [B,H,1024,64]
    gemm_bt<0><<<dim3(64, 4), 256, 0, stream>>>(xc, Wbf, Qw, 1024, 2048, 1024);
    // K: M=16384, out [B,H,2048,64]
    gemm_bt<0><<<dim3(128, 4), 256, 0, stream>>>(xc, Wbf + 262144, Kw, 2048, 2048, 2048);
    // V: M=16384, out transposed [B,H,64,2048]
    gemm_bt<1><<<dim3(128, 4), 256, 0, stream>>>(xc, Wbf + 2 * 262144, Vtw, 2048, 2048, 2048);
    // mask pack (after V gemm: overwrites xc region)
    cvt_mask<<<65536, 256, 0, stream>>>(mask, Mbp);
    // attention
    flash<<<1024, 256, 0, stream>>>(Qw, Kw, Vtw, Mbp, Yb);
    // output projection -> fp32 d_out
    gemm_bt<2><<<dim3(64, 4), 256, 0, stream>>>(Yb, Wbf + 3 * 262144, d_out, 8192, 8192, 8192);
}

// Round 5
// 312.354 us; speedup vs baseline: 1.1877x; 1.1877x over previous
//
#include <hip/hip_runtime.h>
#include <hip/hip_bf16.h>
#include <stdint.h>

typedef __bf16 v8bf __attribute__((ext_vector_type(8)));
typedef float f32x4 __attribute__((ext_vector_type(4)));

__device__ __forceinline__ void gload_lds16(const void* g, void* l) {
    __builtin_amdgcn_global_load_lds(
        (const __attribute__((address_space(1))) void*)g,
        (__attribute__((address_space(3))) void*)l, 16, 0, 0);
}

__device__ __forceinline__ unsigned short f2bf(float f) {
    __hip_bfloat16 h = __float2bfloat16(f);
    return __builtin_bit_cast(unsigned short, h);
}

// ---- fused conversion: xc = concat(x,c) bf16 [8][2048][512]; Wbf = 4 weights bf16
// blocks 0..8191: xc (2,097,152 float4 groups). blocks 8192..9215: weights.
__global__ __launch_bounds__(256) void cvt_xcw(const float* __restrict__ x,
                                               const float* __restrict__ c,
                                               const float* __restrict__ wq,
                                               const float* __restrict__ wk,
                                               const float* __restrict__ wv,
                                               const float* __restrict__ wp,
                                               __hip_bfloat16* __restrict__ xc,
                                               __hip_bfloat16* __restrict__ wout) {
    int bid = blockIdx.x;
    if (bid < 8192) {
        int i = bid * 256 + threadIdx.x;          // float4 index
        long e = (long)i * 4;
        int b = (int)(e >> 20);
        int rem = (int)(e & ((1 << 20) - 1));
        int r = rem >> 9;
        int col = rem & 511;
        const float* src = (r < 1024) ? (x + ((long)b << 19) + (long)r * 512 + col)
                                      : (c + ((long)b << 19) + (long)(r - 1024) * 512 + col);
        float4 v = *(const float4*)src;
        ushort4 o;
        o.x = f2bf(v.x); o.y = f2bf(v.y); o.z = f2bf(v.z); o.w = f2bf(v.w);
        ((ushort4*)xc)[i] = o;
    } else {
        int i = (bid - 8192) * 256 + threadIdx.x; // float4 index, 262,144 total
        int e = i * 4;
        int w = e >> 18;
        int off = e & ((1 << 18) - 1);
        const float* src = (w == 0 ? wq : w == 1 ? wk : w == 2 ? wv : wp) + off;
        float4 val = *(const float4*)src;
        ushort4 o;
        o.x = f2bf(val.x); o.y = f2bf(val.y); o.z = f2bf(val.z); o.w = f2bf(val.w);
        ((ushort4*)wout)[i] = o;
    }
}

// mask int32 [8][1024][2048] -> bit-packed uint64 [8][1024][32]
__global__ __launch_bounds__(256) void cvt_mask(const int* __restrict__ mask,
                                                unsigned long long* __restrict__ mb) {
    long i = (long)blockIdx.x * 256 + threadIdx.x;   // 16,777,216 total
    int v = mask[i] != 0;
    unsigned long long bits = __ballot(v);
    if ((threadIdx.x & 63) == 0) mb[i >> 6] = bits;
}

// ---- fused QKV projection GEMM ------------------------------------------
// C[m,n] = sum_k xc[m,k]*Wbf[n,k], M=16384, N=1536 (Wq|Wk|Wv), K=512.
// Epilogue scatters: n<512 -> Q head-split (x rows only), <1024 -> K head-split,
// else V transposed [bh][dh][key].
__global__ __launch_bounds__(256) void gemm_qkv(const __hip_bfloat16* __restrict__ A,
                                                const __hip_bfloat16* __restrict__ Bw,
                                                __hip_bfloat16* __restrict__ Qw,
                                                __hip_bfloat16* __restrict__ Kw,
                                                __hip_bfloat16* __restrict__ Vtw) {
    __shared__ __hip_bfloat16 As[128 * 32];
    __shared__ __hip_bfloat16 Bs[128 * 32];
    const int tid = threadIdx.x;
    const int wave = tid >> 6, lane = tid & 63;
    const int m0 = blockIdx.x * 128, n0 = blockIdx.y * 128;

    const int la = lane >> 2;
    const int kc = (lane & 3) * 8;
    const long ga0 = (long)(m0 + wave * 16 + la) * 512 + kc;
    const long ga1 = (long)(m0 + (wave + 4) * 16 + la) * 512 + kc;
    const long gb0 = (long)(n0 + wave * 16 + la) * 512 + kc;
    const long gb1 = (long)(n0 + (wave + 4) * 16 + la) * 512 + kc;

    f32x4 acc[4][4] = {};
    const int mw = (wave & 1) * 64, nw = (wave >> 1) * 64;
    const int lrow = lane & 15, lk = (lane >> 4) * 8;

    for (int k0 = 0; k0 < 512; k0 += 32) {
        gload_lds16(A + ga0 + k0, &As[wave * 512]);
        gload_lds16(A + ga1 + k0, &As[(wave + 4) * 512]);
        gload_lds16(Bw + gb0 + k0, &Bs[wave * 512]);
        gload_lds16(Bw + gb1 + k0, &Bs[(wave + 4) * 512]);
        __syncthreads();
        v8bf a[4], b[4];
#pragma unroll
        for (int i = 0; i < 4; i++) {
            a[i] = *(const v8bf*)&As[(mw + i * 16 + lrow) * 32 + lk];
            b[i] = *(const v8bf*)&Bs[(nw + i * 16 + lrow) * 32 + lk];
        }
#pragma unroll
        for (int mi = 0; mi < 4; mi++)
#pragma unroll
            for (int ni = 0; ni < 4; ni++)
                acc[mi][ni] = __builtin_amdgcn_mfma_f32_16x16x32_bf16(a[mi], b[ni], acc[mi][ni], 0, 0, 0);
        __syncthreads();
    }

    const int lq = lane >> 4;
#pragma unroll
    for (int mi = 0; mi < 4; mi++) {
#pragma unroll
        for (int ni = 0; ni < 4; ni++) {
#pragma unroll
            for (int r = 0; r < 4; r++) {
                int grow = m0 + mw + mi * 16 + lq * 4 + r;
                int gcol = n0 + nw + ni * 16 + lrow;
                float val = acc[mi][ni][r];
                int w = gcol >> 9, g9 = gcol & 511;
                int h = g9 >> 6, dh = g9 & 63;
                int b_ = grow >> 11, rr = grow & 2047;
                __hip_bfloat16 bv = __float2bfloat16(val);
                if (w == 0) {
                    if (rr < 1024)
                        Qw[((long)(b_ * 8 + h) * 1024 + rr) * 64 + dh] = bv;
                } else if (w == 1) {
                    Kw[((long)(b_ * 8 + h) * 2048 + rr) * 64 + dh] = bv;
                } else {
                    Vtw[((long)(b_ * 8 + h) * 64 + dh) * 2048 + rr] = bv;
                }
            }
        }
    }
}

// ---- output projection GEMM: d_out[m,n] = sum_k Yb[m,k]*Wp[n,k], fp32 out
__global__ __launch_bounds__(256) void gemm_out(const __hip_bfloat16* __restrict__ A,
                                                const __hip_bfloat16* __restrict__ Bw,
                                                float* __restrict__ outp) {
    __shared__ __hip_bfloat16 As[128 * 32];
    __shared__ __hip_bfloat16 Bs[128 * 32];
    const int tid = threadIdx.x;
    const int wave = tid >> 6, lane = tid & 63;
    const int m0 = blockIdx.x * 128, n0 = blockIdx.y * 128;

    const int la = lane >> 2;
    const int kc = (lane & 3) * 8;
    const long ga0 = (long)(m0 + wave * 16 + la) * 512 + kc;
    const long ga1 = (long)(m0 + (wave + 4) * 16 + la) * 512 + kc;
    const long gb0 = (long)(n0 + wave * 16 + la) * 512 + kc;
    const long gb1 = (long)(n0 + (wave + 4) * 16 + la) * 512 + kc;

    f32x4 acc[4][4] = {};
    const int mw = (wave & 1) * 64, nw = (wave >> 1) * 64;
    const int lrow = lane & 15, lk = (lane >> 4) * 8;

    for (int k0 = 0; k0 < 512; k0 += 32) {
        gload_lds16(A + ga0 + k0, &As[wave * 512]);
        gload_lds16(A + ga1 + k0, &As[(wave + 4) * 512]);
        gload_lds16(Bw + gb0 + k0, &Bs[wave * 512]);
        gload_lds16(Bw + gb1 + k0, &Bs[(wave + 4) * 512]);
        __syncthreads();
        v8bf a[4], b[4];
#pragma unroll
        for (int i = 0; i < 4; i++) {
            a[i] = *(const v8bf*)&As[(mw + i * 16 + lrow) * 32 + lk];
            b[i] = *(const v8bf*)&Bs[(nw + i * 16 + lrow) * 32 + lk];
        }
#pragma unroll
        for (int mi = 0; mi < 4; mi++)
#pragma unroll
            for (int ni = 0; ni < 4; ni++)
                acc[mi][ni] = __builtin_amdgcn_mfma_f32_16x16x32_bf16(a[mi], b[ni], acc[mi][ni], 0, 0, 0);
        __syncthreads();
    }

    const int lq = lane >> 4;
#pragma unroll
    for (int mi = 0; mi < 4; mi++)
#pragma unroll
        for (int ni = 0; ni < 4; ni++)
#pragma unroll
            for (int r = 0; r < 4; r++) {
                int grow = m0 + mw + mi * 16 + lq * 4 + r;
                int gcol = n0 + nw + ni * 16 + lrow;
                outp[(long)grow * 512 + gcol] = acc[mi][ni][r];
            }
}

// ---- flash attention ----------------------------------------------------
// grid 1024, XCD-swizzled (b = L&7). 4 waves; wave owns 16 q-rows.
// No-max softmax (clamped exp, deferred sum reduction) — no shuffles/rescale in loop.
// Q fragments register-resident; LDS only K/V tiles + P round-trip (27.6 KB).
__global__ __launch_bounds__(256) void flash(const __hip_bfloat16* __restrict__ Q,
                                             const __hip_bfloat16* __restrict__ K,
                                             const __hip_bfloat16* __restrict__ Vt,
                                             const unsigned long long* __restrict__ Mb,
                                             __hip_bfloat16* __restrict__ Y) {
    constexpr int LDT = 72;
    __shared__ __hip_bfloat16 Ks[64 * LDT], Vts[64 * LDT];
    __shared__ __hip_bfloat16 Ps[4][16 * LDT];

    const int L = blockIdx.x;
    const int b = L & 7, h = L >> 7, qt = (L >> 3) & 15;
    const int bh = b * 8 + h;
    const int tid = threadIdx.x, wave = tid >> 6, lane = tid & 63;
    const __hip_bfloat16* Qp = Q + ((long)bh * 1024 + qt * 64) * 64;
    const __hip_bfloat16* Kp = K + (long)bh * 2048 * 64;
    const __hip_bfloat16* Vp = Vt + (long)bh * 64 * 2048;
    const unsigned long long* Mp = Mb + ((long)b * 1024 + qt * 64) * 32;

    const int lcol = lane & 15, lq = lane >> 4;

    // Q fragments direct from global (row = wave*16+lcol, k = ks*32+lq*8)
    v8bf aq[2];
#pragma unroll
    for (int ks = 0; ks < 2; ks++)
        aq[ks] = *(const v8bf*)(Qp + (wave * 16 + lcol) * 64 + ks * 32 + lq * 8);

    float lsum[4] = {0.f, 0.f, 0.f, 0.f};
    f32x4 Oacc[4] = {};

    for (int kt = 0; kt < 32; kt++) {
        unsigned long long mbits[4];
#pragma unroll
        for (int r = 0; r < 4; r++)
            mbits[r] = Mp[(wave * 16 + lq * 4 + r) * 32 + kt] >> lcol;

        {   // stage K tile [64 key][64 dh] and V^T tile [64 dh][64 key]
            const uint4* src = (const uint4*)(Kp + kt * 64 * 64);
#pragma unroll
            for (int i = 0; i < 2; i++) {
                int u = tid + i * 256, r = u >> 3, part = u & 7;
                *(uint4*)&Ks[r * LDT + part * 8] = src[u];
            }
#pragma unroll
            for (int i = 0; i < 2; i++) {
                int u = tid + i * 256, dh = u >> 3, part = u & 7;
                *(uint4*)&Vts[dh * LDT + part * 8] = *(const uint4*)(Vp + (long)dh * 2048 + kt * 64 + part * 8);
            }
        }
        __syncthreads();

        // S = Q K^T
        f32x4 S[4] = {};
#pragma unroll
        for (int ks = 0; ks < 2; ks++) {
#pragma unroll
            for (int nt = 0; nt < 4; nt++) {
                v8bf bk = *(const v8bf*)&Ks[(nt * 16 + lcol) * LDT + ks * 32 + lq * 8];
                S[nt] = __builtin_amdgcn_mfma_f32_16x16x32_bf16(aq[ks], bk, S[nt], 0, 0, 0);
            }
        }
        // p = mask ? 0 : exp(s/8)  (clamped; no max-subtraction needed)
        float p[4][4];
#pragma unroll
        for (int nt = 0; nt < 4; nt++)
#pragma unroll
            for (int r = 0; r < 4; r++) {
                float s = fminf(S[nt][r] * 0.125f, 40.f);
                float e = __expf(s);
                e = ((mbits[r] >> (nt * 16)) & 1ull) ? 0.f : e;
                p[nt][r] = e;
                lsum[r] += e;
            }
        // P -> LDS (wave-private) for A-operand reload
#pragma unroll
        for (int nt = 0; nt < 4; nt++)
#pragma unroll
            for (int r = 0; r < 4; r++)
                Ps[wave][(lq * 4 + r) * LDT + nt * 16 + lcol] = __float2bfloat16(p[nt][r]);

        // O += P @ V
#pragma unroll
        for (int ks = 0; ks < 2; ks++) {
            v8bf ap = *(const v8bf*)&Ps[wave][lcol * LDT + ks * 32 + lq * 8];
#pragma unroll
            for (int nt = 0; nt < 4; nt++) {
                v8bf bv = *(const v8bf*)&Vts[(nt * 16 + lcol) * LDT + ks * 32 + lq * 8];
                Oacc[nt] = __builtin_amdgcn_mfma_f32_16x16x32_bf16(ap, bv, Oacc[nt], 0, 0, 0);
            }
        }
        __syncthreads();
    }

    // deferred row-sum reduction across the 16-lane group
#pragma unroll
    for (int r = 0; r < 4; r++) {
        float s = lsum[r];
        s += __shfl_xor(s, 1);
        s += __shfl_xor(s, 2);
        s += __shfl_xor(s, 4);
        s += __shfl_xor(s, 8);
        lsum[r] = s;
    }

    // epilogue: y[b, q, h*64+dh] bf16
#pragma unroll
    for (int r = 0; r < 4; r++) {
        float inv = 1.f / lsum[r];
#pragma unroll
        for (int nt = 0; nt < 4; nt++) {
            long row = (long)b * 1024 + qt * 64 + wave * 16 + lq * 4 + r;
            int col = h * 64 + nt * 16 + lcol;
            Y[row * 512 + col] = __float2bfloat16(Oacc[nt][r] * inv);
        }
    }
}

// ---- launch -------------------------------------------------------------
extern "C" void kernel_launch(void* const* d_in, const int* in_sizes, int n_in,
                              void* d_out, int out_size, void* d_ws, size_t ws_size,
                              hipStream_t stream) {
    const float* x = (const float*)d_in[0];
    const float* c = (const float*)d_in[1];
    const int* mask = (const int*)d_in[2];
    const float* Wq = (const float*)d_in[3];
    const float* Wk = (const float*)d_in[4];
    const float* Wv = (const float*)d_in[5];
    const float* Wp = (const float*)d_in[6];

    char* ws = (char*)d_ws;
    __hip_bfloat16* xc  = (__hip_bfloat16*)(ws);                 // 16,777,216 B (dead after gemm_qkv)
    __hip_bfloat16* Wbf = (__hip_bfloat16*)(ws + 16777216);      //  2,097,152 B
    __hip_bfloat16* Qw  = (__hip_bfloat16*)(ws + 18874368);      //  8,388,608 B
    __hip_bfloat16* Kw  = (__hip_bfloat16*)(ws + 27262976);      // 16,777,216 B
    __hip_bfloat16* Vtw = (__hip_bfloat16*)(ws + 44040192);      // 16,777,216 B
    __hip_bfloat16* Yb  = (__hip_bfloat16*)(ws + 60817408);      //  8,388,608 B
    unsigned long long* Mbp = (unsigned long long*)(ws);         //  2,097,152 B, aliases dead xc

    cvt_xcw<<<9216, 256, 0, stream>>>(x, c, Wq, Wk, Wv, Wp, xc, Wbf);
    gemm_qkv<<<dim3(128, 12), 256, 0, stream>>>(xc, Wbf, Qw, Kw, Vtw);
    cvt_mask<<<65536, 256, 0, stream>>>(mask, Mbp);   // after gemm_qkv: overwrites xc
    flash<<<1024, 256, 0, stream>>>(Qw, Kw, Vtw, Mbp, Yb);
    gemm_out<<<dim3(64, 4), 256, 0, stream>>>(Yb, Wbf + 3 * 262144, (float*)d_out);
}

// Round 6
// 297.232 us; speedup vs baseline: 1.2482x; 1.0509x over previous
//
#include <hip/hip_runtime.h>
#include <hip/hip_bf16.h>
#include <stdint.h>

typedef __bf16 v8bf __attribute__((ext_vector_type(8)));
typedef float f32x4 __attribute__((ext_vector_type(4)));

__device__ __forceinline__ void gload_lds16(const void* g, void* l) {
    __builtin_amdgcn_global_load_lds(
        (const __attribute__((address_space(1))) void*)g,
        (__attribute__((address_space(3))) void*)l, 16, 0, 0);
}

__device__ __forceinline__ unsigned short f2bf(float f) {
    __hip_bfloat16 h = __float2bfloat16(f);
    return __builtin_bit_cast(unsigned short, h);
}

// ---- fused conversion: xc = concat(x,c) bf16 [8][2048][512]; Wbf = 4 weights
__global__ __launch_bounds__(256) void cvt_xcw(const float* __restrict__ x,
                                               const float* __restrict__ c,
                                               const float* __restrict__ wq,
                                               const float* __restrict__ wk,
                                               const float* __restrict__ wv,
                                               const float* __restrict__ wp,
                                               __hip_bfloat16* __restrict__ xc,
                                               __hip_bfloat16* __restrict__ wout) {
    int bid = blockIdx.x;
    if (bid < 8192) {
        int i = bid * 256 + threadIdx.x;
        long e = (long)i * 4;
        int b = (int)(e >> 20);
        int rem = (int)(e & ((1 << 20) - 1));
        int r = rem >> 9;
        int col = rem & 511;
        const float* src = (r < 1024) ? (x + ((long)b << 19) + (long)r * 512 + col)
                                      : (c + ((long)b << 19) + (long)(r - 1024) * 512 + col);
        float4 v = *(const float4*)src;
        ushort4 o;
        o.x = f2bf(v.x); o.y = f2bf(v.y); o.z = f2bf(v.z); o.w = f2bf(v.w);
        ((ushort4*)xc)[i] = o;
    } else {
        int i = (bid - 8192) * 256 + threadIdx.x;
        int e = i * 4;
        int w = e >> 18;
        int off = e & ((1 << 18) - 1);
        const float* src = (w == 0 ? wq : w == 1 ? wk : w == 2 ? wv : wp) + off;
        float4 val = *(const float4*)src;
        ushort4 o;
        o.x = f2bf(val.x); o.y = f2bf(val.y); o.z = f2bf(val.z); o.w = f2bf(val.w);
        ((ushort4*)wout)[i] = o;
    }
}

// mask int32 -> bit-packed uint64 [8][1024][32]; 4 segments per block
__global__ __launch_bounds__(256) void cvt_mask(const int* __restrict__ mask,
                                                unsigned long long* __restrict__ mb) {
    int t = threadIdx.x;
    long base = (long)blockIdx.x * 1024;
#pragma unroll
    for (int j = 0; j < 4; j++) {
        long i = base + j * 256 + t;
        int v = mask[i] != 0;
        unsigned long long bits = __ballot(v);
        if ((t & 63) == 0) mb[i >> 6] = bits;
    }
}

// ---- fused QKV projection GEMM ------------------------------------------
// C[m,n] = sum_k xc[m,k]*Wbf[n,k], M=16384, N=1536. by<8: Q/K head-split
// scatter. by>=8 (V): LDS-transpose epilogue -> coalesced V^T stores.
__global__ __launch_bounds__(256) void gemm_qkv(const __hip_bfloat16* __restrict__ A,
                                                const __hip_bfloat16* __restrict__ Bw,
                                                __hip_bfloat16* __restrict__ Qw,
                                                __hip_bfloat16* __restrict__ Kw,
                                                __hip_bfloat16* __restrict__ Vtw) {
    __shared__ union {
        struct { __hip_bfloat16 As[128 * 32]; __hip_bfloat16 Bs[128 * 32]; } s;
        __hip_bfloat16 T[128 * 136];   // transpose buffer [n][m], stride 136 (16B-aligned rows)
    } u;
    const int tid = threadIdx.x;
    const int wave = tid >> 6, lane = tid & 63;
    const int m0 = blockIdx.x * 128, n0 = blockIdx.y * 128;

    const int la = lane >> 2;
    const int kc = (lane & 3) * 8;
    const long ga0 = (long)(m0 + wave * 16 + la) * 512 + kc;
    const long ga1 = (long)(m0 + (wave + 4) * 16 + la) * 512 + kc;
    const long gb0 = (long)(n0 + wave * 16 + la) * 512 + kc;
    const long gb1 = (long)(n0 + (wave + 4) * 16 + la) * 512 + kc;

    f32x4 acc[4][4] = {};
    const int mw = (wave & 1) * 64, nw = (wave >> 1) * 64;
    const int lrow = lane & 15, lk = (lane >> 4) * 8;

    for (int k0 = 0; k0 < 512; k0 += 32) {
        gload_lds16(A + ga0 + k0, &u.s.As[wave * 512]);
        gload_lds16(A + ga1 + k0, &u.s.As[(wave + 4) * 512]);
        gload_lds16(Bw + gb0 + k0, &u.s.Bs[wave * 512]);
        gload_lds16(Bw + gb1 + k0, &u.s.Bs[(wave + 4) * 512]);
        __syncthreads();
        v8bf a[4], b[4];
#pragma unroll
        for (int i = 0; i < 4; i++) {
            a[i] = *(const v8bf*)&u.s.As[(mw + i * 16 + lrow) * 32 + lk];
            b[i] = *(const v8bf*)&u.s.Bs[(nw + i * 16 + lrow) * 32 + lk];
        }
#pragma unroll
        for (int mi = 0; mi < 4; mi++)
#pragma unroll
            for (int ni = 0; ni < 4; ni++)
                acc[mi][ni] = __builtin_amdgcn_mfma_f32_16x16x32_bf16(a[mi], b[ni], acc[mi][ni], 0, 0, 0);
        __syncthreads();
    }

    const int lq = lane >> 4;
    if (blockIdx.y < 8) {
        // Q/K head-split scatter
#pragma unroll
        for (int mi = 0; mi < 4; mi++)
#pragma unroll
            for (int ni = 0; ni < 4; ni++)
#pragma unroll
                for (int r = 0; r < 4; r++) {
                    int grow = m0 + mw + mi * 16 + lq * 4 + r;
                    int gcol = n0 + nw + ni * 16 + lrow;
                    int w = gcol >> 9, g9 = gcol & 511;
                    int h = g9 >> 6, dh = g9 & 63;
                    int b_ = grow >> 11, rr = grow & 2047;
                    __hip_bfloat16 bv = __float2bfloat16(acc[mi][ni][r]);
                    if (w == 0) {
                        if (rr < 1024)
                            Qw[((long)(b_ * 8 + h) * 1024 + rr) * 64 + dh] = bv;
                    } else {
                        Kw[((long)(b_ * 8 + h) * 2048 + rr) * 64 + dh] = bv;
                    }
                }
    } else {
        // V: transpose in LDS, store coalesced V^T rows
#pragma unroll
        for (int mi = 0; mi < 4; mi++)
#pragma unroll
            for (int ni = 0; ni < 4; ni++) {
                int n_l = nw + ni * 16 + lrow;
                int m_l = mw + mi * 16 + lq * 4;
                ushort4 pk;
                pk.x = f2bf(acc[mi][ni][0]); pk.y = f2bf(acc[mi][ni][1]);
                pk.z = f2bf(acc[mi][ni][2]); pk.w = f2bf(acc[mi][ni][3]);
                *(ushort4*)&u.T[n_l * 136 + m_l] = pk;
            }
        __syncthreads();
        const int no = (blockIdx.y - 8) * 128;
        const int b_ = m0 >> 11, rrb = m0 & 2047;
#pragma unroll
        for (int i = 0; i < 8; i++) {
            int s = tid + i * 256;         // 2048 slots: 128 n-rows x 16 chunks
            int n_l = s >> 4, ch = s & 15;
            int ng = no + n_l;
            int h = ng >> 6, dh = ng & 63;
            uint4 v = *(const uint4*)&u.T[n_l * 136 + ch * 8];
            *(uint4*)&Vtw[((long)(b_ * 8 + h) * 64 + dh) * 2048 + rrb + ch * 8] = v;
        }
    }
}

// ---- output projection GEMM: d_out[m,n] = sum_k Yb[m,k]*Wp[n,k], fp32 out
__global__ __launch_bounds__(256) void gemm_out(const __hip_bfloat16* __restrict__ A,
                                                const __hip_bfloat16* __restrict__ Bw,
                                                float* __restrict__ outp) {
    __shared__ __hip_bfloat16 As[128 * 32];
    __shared__ __hip_bfloat16 Bs[128 * 32];
    const int tid = threadIdx.x;
    const int wave = tid >> 6, lane = tid & 63;
    const int m0 = blockIdx.x * 128, n0 = blockIdx.y * 128;

    const int la = lane >> 2;
    const int kc = (lane & 3) * 8;
    const long ga0 = (long)(m0 + wave * 16 + la) * 512 + kc;
    const long ga1 = (long)(m0 + (wave + 4) * 16 + la) * 512 + kc;
    const long gb0 = (long)(n0 + wave * 16 + la) * 512 + kc;
    const long gb1 = (long)(n0 + (wave + 4) * 16 + la) * 512 + kc;

    f32x4 acc[4][4] = {};
    const int mw = (wave & 1) * 64, nw = (wave >> 1) * 64;
    const int lrow = lane & 15, lk = (lane >> 4) * 8;

    for (int k0 = 0; k0 < 512; k0 += 32) {
        gload_lds16(A + ga0 + k0, &As[wave * 512]);
        gload_lds16(A + ga1 + k0, &As[(wave + 4) * 512]);
        gload_lds16(Bw + gb0 + k0, &Bs[wave * 512]);
        gload_lds16(Bw + gb1 + k0, &Bs[(wave + 4) * 512]);
        __syncthreads();
        v8bf a[4], b[4];
#pragma unroll
        for (int i = 0; i < 4; i++) {
            a[i] = *(const v8bf*)&As[(mw + i * 16 + lrow) * 32 + lk];
            b[i] = *(const v8bf*)&Bs[(nw + i * 16 + lrow) * 32 + lk];
        }
#pragma unroll
        for (int mi = 0; mi < 4; mi++)
#pragma unroll
            for (int ni = 0; ni < 4; ni++)
                acc[mi][ni] = __builtin_amdgcn_mfma_f32_16x16x32_bf16(a[mi], b[ni], acc[mi][ni], 0, 0, 0);
        __syncthreads();
    }

    const int lq = lane >> 4;
#pragma unroll
    for (int mi = 0; mi < 4; mi++)
#pragma unroll
        for (int ni = 0; ni < 4; ni++)
#pragma unroll
            for (int r = 0; r < 4; r++) {
                int grow = m0 + mw + mi * 16 + lq * 4 + r;
                int gcol = n0 + nw + ni * 16 + lrow;
                outp[(long)grow * 512 + gcol] = acc[mi][ni][r];
            }
}

// ---- flash attention, key-split waves, barrier-free K-loop ---------------
// grid 1024 (b=L&7 XCD-pinned, qt=(L>>3)&15, h=L>>7). Block = 4 waves, 64 q.
// Wave w owns keys {128kt + 64kt2 + 16w + [0,16)}. K/V frags load DIRECT from
// global (L2-resident). LDS: only wave-private P transpose (16KB, XOR-swizzled)
// + final O reduction (reuses P buffer) + lsum array.
__global__ __launch_bounds__(256) void flash(const __hip_bfloat16* __restrict__ Q,
                                             const __hip_bfloat16* __restrict__ K,
                                             const __hip_bfloat16* __restrict__ Vt,
                                             const unsigned long long* __restrict__ Mb,
                                             __hip_bfloat16* __restrict__ Y) {
    __shared__ __hip_bfloat16 Ps[4][64 * 32];   // [wave][q 64][key 32], 16B-chunk XOR swizzle
    __shared__ float Ls[4][64];                 // per-wave row sums

    const int L = blockIdx.x;
    const int b = L & 7, h = L >> 7, qt = (L >> 3) & 15;
    const int bh = b * 8 + h;
    const int tid = threadIdx.x, w = tid >> 6, lane = tid & 63;
    const int lcol = lane & 15, lq = lane >> 4;

    const __hip_bfloat16* Qp = Q + ((long)bh * 1024 + qt * 64) * 64;
    const __hip_bfloat16* Kp = K + ((long)bh * 2048 + w * 16 + lcol) * 64;  // A-frag row base
    const __hip_bfloat16* Vp = Vt + (long)bh * 64 * 2048;
    const unsigned long long* Mp = Mb + ((long)b * 1024 + qt * 64) * 32;

    // Q B-frags (all 64 q rows), register-resident
    v8bf bq[4][2];
#pragma unroll
    for (int mi = 0; mi < 4; mi++)
#pragma unroll
        for (int ks = 0; ks < 2; ks++)
            bq[mi][ks] = *(const v8bf*)(Qp + (mi * 16 + lcol) * 64 + ks * 32 + lq * 8);

    f32x4 Oacc[4][4] = {};
    float lsum[4] = {0.f, 0.f, 0.f, 0.f};
    const int vkey = (lq >> 1) * 64 + w * 16 + (lq & 1) * 8;  // B-frag key base within 128-tile
    const int mshift = w * 16 + lq * 4;                       // mask shift for C-layout keys

    for (int kt = 0; kt < 16; kt++) {
        // mask words (one per (q-tile mi, 64-key half kt2))
        unsigned long long mb_[4][2];
#pragma unroll
        for (int mi = 0; mi < 4; mi++)
#pragma unroll
            for (int kt2 = 0; kt2 < 2; kt2++)
                mb_[mi][kt2] = Mp[(mi * 16 + lcol) * 32 + kt * 2 + kt2] >> mshift;

        // K A-frags: A[m=key=w*16+lcol][k=d]
        v8bf ak[2][2];
#pragma unroll
        for (int kt2 = 0; kt2 < 2; kt2++)
#pragma unroll
            for (int ks = 0; ks < 2; ks++)
                ak[kt2][ks] = *(const v8bf*)(Kp + (long)(kt * 128 + kt2 * 64) * 64 + ks * 32 + lq * 8);

        // V B-frags: B[n=d=nd*16+lcol][k=key]
        v8bf bv[4];
#pragma unroll
        for (int nd = 0; nd < 4; nd++)
            bv[nd] = *(const v8bf*)(Vp + (long)(nd * 16 + lcol) * 2048 + kt * 128 + vkey);

        // S^T = K Q^T per (kt2, mi); exp; pack into Ps
#pragma unroll
        for (int kt2 = 0; kt2 < 2; kt2++)
#pragma unroll
            for (int mi = 0; mi < 4; mi++) {
                f32x4 st = {};
                st = __builtin_amdgcn_mfma_f32_16x16x32_bf16(ak[kt2][0], bq[mi][0], st, 0, 0, 0);
                st = __builtin_amdgcn_mfma_f32_16x16x32_bf16(ak[kt2][1], bq[mi][1], st, 0, 0, 0);
                ushort4 pk;
                float e;
#pragma unroll
                for (int r = 0; r < 4; r++) {
                    float s = fminf(st[r] * 0.125f, 40.f);
                    e = __expf(s);
                    e = ((mb_[mi][kt2] >> r) & 1ull) ? 0.f : e;
                    lsum[mi] += e;
                    ((unsigned short*)&pk)[r] = f2bf(e);
                }
                int row = mi * 16 + lcol;                       // q
                int ch = (kt2 * 2 + (lq >> 1)) ^ (row & 3);     // 16B chunk swizzle
                *(ushort4*)((char*)&Ps[w][0] + row * 64 + ch * 16 + (lq & 1) * 8) = pk;
            }

        // PV: O[q][d] += P[q][key] V^T[d][key]
#pragma unroll
        for (int mi = 0; mi < 4; mi++) {
            int row = mi * 16 + lcol;
            v8bf ap = *(const v8bf*)((char*)&Ps[w][0] + row * 64 + ((lq ^ (row & 3)) * 16));
#pragma unroll
            for (int nd = 0; nd < 4; nd++)
                Oacc[mi][nd] = __builtin_amdgcn_mfma_f32_16x16x32_bf16(ap, bv[nd], Oacc[mi][nd], 0, 0, 0);
        }
    }

    // lsum: reduce over lq groups (lanes lcol+16*lq), then publish per wave
#pragma unroll
    for (int mi = 0; mi < 4; mi++) {
        float s = lsum[mi];
        s += __shfl_xor(s, 16);
        s += __shfl_xor(s, 32);
        lsum[mi] = s;
    }
    if (lq == 0) {
#pragma unroll
        for (int mi = 0; mi < 4; mi++) Ls[w][mi * 16 + lcol] = lsum[mi];
    }
    __syncthreads();   // Ps dead, Ls visible

    // cross-wave O reduction: serial add-chain through Of (reuses Ps, 16KB f32)
    float* Of = (float*)&Ps[0][0];
    if (w == 0) {
#pragma unroll
        for (int mi = 0; mi < 4; mi++)
#pragma unroll
            for (int nd = 0; nd < 4; nd++)
#pragma unroll
                for (int r = 0; r < 4; r++)
                    Of[(mi * 16 + lq * 4 + r) * 64 + nd * 16 + lcol] = Oacc[mi][nd][r];
    }
    __syncthreads();
    if (w == 1) {
#pragma unroll
        for (int mi = 0; mi < 4; mi++)
#pragma unroll
            for (int nd = 0; nd < 4; nd++)
#pragma unroll
                for (int r = 0; r < 4; r++) {
                    int idx = (mi * 16 + lq * 4 + r) * 64 + nd * 16 + lcol;
                    Of[idx] += Oacc[mi][nd][r];
                }
    }
    __syncthreads();
    if (w == 2) {
#pragma unroll
        for (int mi = 0; mi < 4; mi++)
#pragma unroll
            for (int nd = 0; nd < 4; nd++)
#pragma unroll
                for (int r = 0; r < 4; r++) {
                    int idx = (mi * 16 + lq * 4 + r) * 64 + nd * 16 + lcol;
                    Of[idx] += Oacc[mi][nd][r];
                }
    }
    __syncthreads();
    if (w == 3) {
#pragma unroll
        for (int mi = 0; mi < 4; mi++)
#pragma unroll
            for (int r = 0; r < 4; r++) {
                int q = mi * 16 + lq * 4 + r;
                float rs = Ls[0][q] + Ls[1][q] + Ls[2][q] + Ls[3][q];
                float inv = 1.f / rs;
                long row = (long)b * 1024 + qt * 64 + q;
#pragma unroll
                for (int nd = 0; nd < 4; nd++) {
                    int idx = q * 64 + nd * 16 + lcol;
                    float val = (Oacc[mi][nd][r] + Of[idx]) * inv;
                    Y[row * 512 + h * 64 + nd * 16 + lcol] = __float2bfloat16(val);
                }
            }
    }
}

// ---- launch -------------------------------------------------------------
extern "C" void kernel_launch(void* const* d_in, const int* in_sizes, int n_in,
                              void* d_out, int out_size, void* d_ws, size_t ws_size,
                              hipStream_t stream) {
    const float* x = (const float*)d_in[0];
    const float* c = (const float*)d_in[1];
    const int* mask = (const int*)d_in[2];
    const float* Wq = (const float*)d_in[3];
    const float* Wk = (const float*)d_in[4];
    const float* Wv = (const float*)d_in[5];
    const float* Wp = (const float*)d_in[6];

    char* ws = (char*)d_ws;
    __hip_bfloat16* xc  = (__hip_bfloat16*)(ws);                 // 16 MB (dead after gemm_qkv)
    __hip_bfloat16* Wbf = (__hip_bfloat16*)(ws + 16777216);      //  2 MB
    __hip_bfloat16* Qw  = (__hip_bfloat16*)(ws + 18874368);      //  8 MB
    __hip_bfloat16* Kw  = (__hip_bfloat16*)(ws + 27262976);      // 16 MB
    __hip_bfloat16* Vtw = (__hip_bfloat16*)(ws + 44040192);      // 16 MB
    __hip_bfloat16* Yb  = (__hip_bfloat16*)(ws + 60817408);      //  8 MB
    unsigned long long* Mbp = (unsigned long long*)(ws);         //  2 MB, aliases dead xc

    cvt_xcw<<<9216, 256, 0, stream>>>(x, c, Wq, Wk, Wv, Wp, xc, Wbf);
    gemm_qkv<<<dim3(128, 12), 256, 0, stream>>>(xc, Wbf, Qw, Kw, Vtw);
    cvt_mask<<<16384, 256, 0, stream>>>(mask, Mbp);   // after gemm_qkv: overwrites xc
    flash<<<1024, 256, 0, stream>>>(Qw, Kw, Vtw, Mbp, Yb);
    gemm_out<<<dim3(64, 4), 256, 0, stream>>>(Yb, Wbf + 3 * 262144, (float*)d_out);
}